// Round 1
// baseline (64.387 us; speedup 1.0000x reference)
//
#include <hip/hip_runtime.h>
#include <math.h>

#define DIM 512
#define NNBR 8
#define NCTX 16
#define BATCH 1024

// ---------------- K1: hidden[b,d] = self + softmax_k(user.rel_k) * nbr_k ----------------
// one block (512 threads = 8 waves) per batch row; thread t <-> dim d
__global__ __launch_bounds__(512) void k_hidden(
    const int* __restrict__ u, const int* __restrict__ v,
    const int* __restrict__ adj_ent, const int* __restrict__ adj_rel,
    const float* __restrict__ usr_emb, const float* __restrict__ ent_emb,
    const float* __restrict__ rel_emb, float* __restrict__ hidden)
{
    const int b = blockIdx.x;
    const int t = threadIdx.x;           // d index
    __shared__ int s_ne[NNBR], s_nr[NNBR];
    __shared__ float s_sc[NNBR];
    const int vid = v[b];
    const int uid = u[b];
    if (t < NNBR) {
        s_ne[t] = adj_ent[vid * NNBR + t];
        s_nr[t] = adj_rel[vid * NNBR + t];
        s_sc[t] = 0.0f;
    }
    __syncthreads();

    const float user_d = usr_emb[(size_t)uid * DIM + t];
    const float self_d = ent_emb[(size_t)vid * DIM + t];
    float nbr[NNBR], p[NNBR];
#pragma unroll
    for (int k = 0; k < NNBR; ++k) {
        nbr[k] = ent_emb[(size_t)s_ne[k] * DIM + t];
        p[k] = user_d * rel_emb[(size_t)s_nr[k] * DIM + t];
    }
    // wave-level reduce each score partial (64 lanes)
#pragma unroll
    for (int k = 0; k < NNBR; ++k) {
#pragma unroll
        for (int off = 32; off >= 1; off >>= 1)
            p[k] += __shfl_xor(p[k], off, 64);
    }
    if ((t & 63) == 0) {
#pragma unroll
        for (int k = 0; k < NNBR; ++k) atomicAdd(&s_sc[k], p[k]);
    }
    __syncthreads();

    // softmax over 8 neighbors (computed redundantly by every thread)
    float m = s_sc[0];
#pragma unroll
    for (int k = 1; k < NNBR; ++k) m = fmaxf(m, s_sc[k]);
    float e[NNBR], ssum = 0.0f;
#pragma unroll
    for (int k = 0; k < NNBR; ++k) { e[k] = expf(s_sc[k] - m); ssum += e[k]; }
    const float inv = 1.0f / ssum;
    float agg = 0.0f;
#pragma unroll
    for (int k = 0; k < NNBR; ++k) agg = fmaf(e[k], nbr[k], agg);

    hidden[(size_t)b * DIM + t] = self_d + agg * inv;
}

// ---------------- K2: item = tanh(hidden @ W_agg^T + b_agg) ----------------
// fp32 tiled GEMM: C[m][n] = sum_k A[m][k] * B[n][k]  (both row-major, K contiguous)
// 64x64 tile, 256 threads, 4x4 microtile, BK=16, k-major LDS (pad 68 -> <=2-way conflicts)
__global__ __launch_bounds__(256) void k_item(
    const float* __restrict__ hidden, const float* __restrict__ W_agg,
    const float* __restrict__ b_agg, float* __restrict__ item)
{
    __shared__ float As[16][68];
    __shared__ float Bs[16][68];
    const int tid = threadIdx.x;
    const int tx = tid & 15, ty = tid >> 4;
    const int m0 = blockIdx.x * 64, n0 = blockIdx.y * 64;
    const int lrow = tid >> 2, lkq = tid & 3;   // staging coords

    float acc[4][4] = {};

    for (int k0 = 0; k0 < DIM; k0 += 16) {
        const float4 a4 = *(const float4*)&hidden[(size_t)(m0 + lrow) * DIM + k0 + lkq * 4];
        const float4 b4 = *(const float4*)&W_agg [(size_t)(n0 + lrow) * DIM + k0 + lkq * 4];
        __syncthreads();   // previous iteration's compute done before LDS overwrite
        As[lkq * 4 + 0][lrow] = a4.x; As[lkq * 4 + 1][lrow] = a4.y;
        As[lkq * 4 + 2][lrow] = a4.z; As[lkq * 4 + 3][lrow] = a4.w;
        Bs[lkq * 4 + 0][lrow] = b4.x; Bs[lkq * 4 + 1][lrow] = b4.y;
        Bs[lkq * 4 + 2][lrow] = b4.z; Bs[lkq * 4 + 3][lrow] = b4.w;
        __syncthreads();
#pragma unroll
        for (int kk = 0; kk < 16; ++kk) {
            const float4 av = *(const float4*)&As[kk][ty * 4];
            const float4 bv = *(const float4*)&Bs[kk][tx * 4];
            const float a[4] = {av.x, av.y, av.z, av.w};
            const float bb[4] = {bv.x, bv.y, bv.z, bv.w};
#pragma unroll
            for (int i = 0; i < 4; ++i)
#pragma unroll
                for (int j = 0; j < 4; ++j)
                    acc[i][j] = fmaf(a[i], bb[j], acc[i][j]);
        }
    }

#pragma unroll
    for (int i = 0; i < 4; ++i) {
        const int row = m0 + ty * 4 + i;
        float4 o;
        o.x = tanhf(acc[i][0] + b_agg[n0 + tx * 4 + 0]);
        o.y = tanhf(acc[i][1] + b_agg[n0 + tx * 4 + 1]);
        o.z = tanhf(acc[i][2] + b_agg[n0 + tx * 4 + 2]);
        o.w = tanhf(acc[i][3] + b_agg[n0 + tx * 4 + 3]);
        *(float4*)&item[(size_t)row * DIM + n0 + tx * 4] = o;
    }
}

// ---------------- K3: out[b] = sigmoid(dot(user[b], item[b])) ----------------
// 4 waves per block, one wave per b
__global__ __launch_bounds__(256) void k_out(
    const int* __restrict__ u, const float* __restrict__ usr_emb,
    const float* __restrict__ item, float* __restrict__ out)
{
    const int w = threadIdx.x >> 6;
    const int lane = threadIdx.x & 63;
    const int b = blockIdx.x * 4 + w;
    const int uid = u[b];
    float acc = 0.0f;
#pragma unroll
    for (int i = 0; i < DIM / 64; ++i) {
        const int d = lane + i * 64;
        acc = fmaf(usr_emb[(size_t)uid * DIM + d], item[(size_t)b * DIM + d], acc);
    }
#pragma unroll
    for (int off = 32; off >= 1; off >>= 1) acc += __shfl_xor(acc, off, 64);
    if (lane == 0) out[b] = 1.0f / (1.0f + expf(-acc));
}

// ---------------- K4a: partial context GEMM over b-chunks ----------------
// part[ch][n][d] = sum_{b in chunk ch} item[b][d] * W_lin[n][b]
__global__ __launch_bounds__(512) void k_ctx_part(
    const float* __restrict__ item, const float* __restrict__ W_lin,
    float* __restrict__ part)
{
    const int ch = blockIdx.x;        // 16 chunks of 64 rows
    const int d = threadIdx.x;
    float acc[NCTX] = {};
    for (int bb = 0; bb < 64; ++bb) {
        const int b = ch * 64 + bb;
        const float iv = item[(size_t)b * DIM + d];
#pragma unroll
        for (int n = 0; n < NCTX; ++n)
            acc[n] = fmaf(iv, W_lin[n * BATCH + b], acc[n]);   // uniform -> s_load
    }
#pragma unroll
    for (int n = 0; n < NCTX; ++n)
        part[((size_t)ch * NCTX + n) * DIM + d] = acc[n];
}

// ---------------- K4b: c[n][d] = b_lin[n] + sum_ch part[ch][n][d] ----------------
__global__ __launch_bounds__(512) void k_ctx_reduce(
    const float* __restrict__ part, const float* __restrict__ b_lin,
    float* __restrict__ c)
{
    const int n = blockIdx.x, d = threadIdx.x;
    float acc = b_lin[n];
#pragma unroll
    for (int ch = 0; ch < 16; ++ch)
        acc += part[((size_t)ch * NCTX + n) * DIM + d];
    c[(size_t)n * DIM + d] = acc;
}

extern "C" void kernel_launch(void* const* d_in, const int* in_sizes, int n_in,
                              void* d_out, int out_size, void* d_ws, size_t ws_size,
                              hipStream_t stream) {
    const int*   u       = (const int*)  d_in[0];
    const int*   v       = (const int*)  d_in[1];
    const int*   adj_ent = (const int*)  d_in[2];
    const int*   adj_rel = (const int*)  d_in[3];
    const float* usr_emb = (const float*)d_in[4];
    const float* ent_emb = (const float*)d_in[5];
    const float* rel_emb = (const float*)d_in[6];
    const float* W_agg   = (const float*)d_in[7];
    const float* b_agg   = (const float*)d_in[8];
    const float* W_lin   = (const float*)d_in[9];
    const float* b_lin   = (const float*)d_in[10];

    float* out = (float*)d_out;            // [1024]
    float* c   = out + BATCH;              // [16][512]

    // workspace layout: hidden (2MB) | item (2MB) | part (512KB)  => 4.5MB total
    float* hidden = (float*)d_ws;
    float* item   = hidden + (size_t)BATCH * DIM;
    float* part   = item   + (size_t)BATCH * DIM;

    k_hidden<<<BATCH, 512, 0, stream>>>(u, v, adj_ent, adj_rel,
                                        usr_emb, ent_emb, rel_emb, hidden);
    k_item<<<dim3(BATCH / 64, DIM / 64), 256, 0, stream>>>(hidden, W_agg, b_agg, item);
    k_out<<<BATCH / 4, 256, 0, stream>>>(u, usr_emb, item, out);
    k_ctx_part<<<16, 512, 0, stream>>>(item, W_lin, part);
    k_ctx_reduce<<<NCTX, 512, 0, stream>>>(part, b_lin, c);
}

// Round 2
// 50.768 us; speedup vs baseline: 1.2683x; 1.2683x over previous
//
#include <hip/hip_runtime.h>
#include <math.h>

#define DIM 512
#define NNBR 8
#define NCTX 16
#define BATCH 1024

typedef __attribute__((ext_vector_type(8))) short bf16x8;
typedef __attribute__((ext_vector_type(4))) float f32x4;

// RNE float -> bf16 bits
static __device__ __forceinline__ ushort f2bf(float f) {
    uint u = __float_as_uint(f);
    return (ushort)((u + 0x7fffu + ((u >> 16) & 1u)) >> 16);
}

// ---------------- K1: hidden_bf[b,d] = bf16(self + softmax_k(user.rel_k) . nbr_k) ----------------
// one block (512 threads = 8 waves) per batch row; thread t <-> dim d.
// Blocks < 512 also convert one 512-elem slice of W_agg to bf16 (saves a launch).
__global__ __launch_bounds__(512) void k_hidden(
    const int* __restrict__ u, const int* __restrict__ v,
    const int* __restrict__ adj_ent, const int* __restrict__ adj_rel,
    const float* __restrict__ usr_emb, const float* __restrict__ ent_emb,
    const float* __restrict__ rel_emb, const float* __restrict__ W_agg,
    ushort* __restrict__ hidden_bf, ushort* __restrict__ Wb)
{
    const int b = blockIdx.x;
    const int t = threadIdx.x;           // d index
    if (b < 512) {                        // W_agg -> bf16 (512*512 elems total)
        const size_t wi = (size_t)b * 512 + t;
        Wb[wi] = f2bf(W_agg[wi]);
    }
    __shared__ int s_ne[NNBR], s_nr[NNBR];
    __shared__ float s_sc[NNBR];
    const int vid = v[b];
    const int uid = u[b];
    if (t < NNBR) {
        s_ne[t] = adj_ent[vid * NNBR + t];
        s_nr[t] = adj_rel[vid * NNBR + t];
        s_sc[t] = 0.0f;
    }
    __syncthreads();

    const float user_d = usr_emb[(size_t)uid * DIM + t];
    const float self_d = ent_emb[(size_t)vid * DIM + t];
    float nbr[NNBR], p[NNBR];
#pragma unroll
    for (int k = 0; k < NNBR; ++k) {
        nbr[k] = ent_emb[(size_t)s_ne[k] * DIM + t];
        p[k] = user_d * rel_emb[(size_t)s_nr[k] * DIM + t];
    }
#pragma unroll
    for (int k = 0; k < NNBR; ++k) {
#pragma unroll
        for (int off = 32; off >= 1; off >>= 1)
            p[k] += __shfl_xor(p[k], off, 64);
    }
    if ((t & 63) == 0) {
#pragma unroll
        for (int k = 0; k < NNBR; ++k) atomicAdd(&s_sc[k], p[k]);
    }
    __syncthreads();

    float m = s_sc[0];
#pragma unroll
    for (int k = 1; k < NNBR; ++k) m = fmaxf(m, s_sc[k]);
    float e[NNBR], ssum = 0.0f;
#pragma unroll
    for (int k = 0; k < NNBR; ++k) { e[k] = expf(s_sc[k] - m); ssum += e[k]; }
    const float inv = 1.0f / ssum;
    float agg = 0.0f;
#pragma unroll
    for (int k = 0; k < NNBR; ++k) agg = fmaf(e[k], nbr[k], agg);

    hidden_bf[(size_t)b * DIM + t] = f2bf(self_d + agg * inv);
}

// ---------------- K2: item = tanh(hidden @ W_agg^T + b_agg), bf16 MFMA ----------------
// 256 thr = 4 waves (2x2), block tile 64x64, wave tile 32x32 (2x2 frags of 16x16),
// fragments loaded straight from global (A 1MB + B 0.5MB are L2-resident; each
// lane's fragment is one contiguous 16B load -> no LDS needed).
__global__ __launch_bounds__(256) void k_item_mfma(
    const ushort* __restrict__ hidden, const ushort* __restrict__ Wb,
    const float* __restrict__ b_agg, float* __restrict__ item)
{
    const int tid = threadIdx.x;
    const int lane = tid & 63, w = tid >> 6;
    const int wr = w >> 1, wc = w & 1;
    const int m0 = blockIdx.x * 64 + wr * 32;
    const int n0 = blockIdx.y * 64 + wc * 32;
    const int r = lane & 15;             // A-row / B-col within frag
    const int kb = lane >> 4;            // k-block (8 elems each)

    f32x4 acc[2][2] = {};
    const ushort* Ap = hidden + (size_t)(m0 + r) * DIM + kb * 8;
    const ushort* Bp = Wb     + (size_t)(n0 + r) * DIM + kb * 8;

#pragma unroll
    for (int k0 = 0; k0 < DIM; k0 += 32) {
        bf16x8 a0 = *(const bf16x8*)(Ap + k0);
        bf16x8 a1 = *(const bf16x8*)(Ap + 16 * DIM + k0);
        bf16x8 b0 = *(const bf16x8*)(Bp + k0);
        bf16x8 b1 = *(const bf16x8*)(Bp + 16 * DIM + k0);
        acc[0][0] = __builtin_amdgcn_mfma_f32_16x16x32_bf16(a0, b0, acc[0][0], 0, 0, 0);
        acc[0][1] = __builtin_amdgcn_mfma_f32_16x16x32_bf16(a0, b1, acc[0][1], 0, 0, 0);
        acc[1][0] = __builtin_amdgcn_mfma_f32_16x16x32_bf16(a1, b0, acc[1][0], 0, 0, 0);
        acc[1][1] = __builtin_amdgcn_mfma_f32_16x16x32_bf16(a1, b1, acc[1][1], 0, 0, 0);
    }

    const int orow = (lane >> 4) * 4;    // C/D: row=(lane>>4)*4+reg, col=lane&15
#pragma unroll
    for (int mi = 0; mi < 2; ++mi)
#pragma unroll
        for (int ni = 0; ni < 2; ++ni) {
            const int col = n0 + ni * 16 + r;
            const float bias = b_agg[col];
            const f32x4 vacc = acc[mi][ni];
#pragma unroll
            for (int j = 0; j < 4; ++j) {
                const int row = m0 + mi * 16 + orow + j;
                item[(size_t)row * DIM + col] = tanhf(vacc[j] + bias);
            }
        }
}

// ---------------- K3: out[b] = sigmoid(dot(user[b], item[b])) ----------------
__global__ __launch_bounds__(256) void k_out(
    const int* __restrict__ u, const float* __restrict__ usr_emb,
    const float* __restrict__ item, float* __restrict__ out)
{
    const int w = threadIdx.x >> 6;
    const int lane = threadIdx.x & 63;
    const int b = blockIdx.x * 4 + w;
    const int uid = u[b];
    float acc = 0.0f;
#pragma unroll
    for (int i = 0; i < DIM / 64; ++i) {
        const int d = lane + i * 64;
        acc = fmaf(usr_emb[(size_t)uid * DIM + d], item[(size_t)b * DIM + d], acc);
    }
#pragma unroll
    for (int off = 32; off >= 1; off >>= 1) acc += __shfl_xor(acc, off, 64);
    if (lane == 0) out[b] = 1.0f / (1.0f + expf(-acc));
}

// ---------------- K4a: partial context GEMM, 64 chunks of 16 rows ----------------
// part[ch][n][d] = sum_{b in chunk ch} item[b][d] * W_lin[n][b]
__global__ __launch_bounds__(512) void k_ctx_part(
    const float* __restrict__ item, const float* __restrict__ W_lin,
    float* __restrict__ part)
{
    const int ch = blockIdx.x;        // 64 chunks of 16 rows
    const int d = threadIdx.x;
    float acc[NCTX] = {};
    for (int bb = 0; bb < 16; ++bb) {
        const int b = ch * 16 + bb;
        const float iv = item[(size_t)b * DIM + d];
#pragma unroll
        for (int n = 0; n < NCTX; ++n)
            acc[n] = fmaf(iv, W_lin[n * BATCH + b], acc[n]);   // uniform -> s_load
    }
#pragma unroll
    for (int n = 0; n < NCTX; ++n)
        part[((size_t)ch * NCTX + n) * DIM + d] = acc[n];
}

// ---------------- K4b: c[n][d] = b_lin[n] + sum_ch part[ch][n][d] ----------------
// 64 blocks x 128 thr: block handles (n, d-quarter)
__global__ __launch_bounds__(128) void k_ctx_reduce(
    const float* __restrict__ part, const float* __restrict__ b_lin,
    float* __restrict__ c)
{
    const int n = blockIdx.x >> 2;
    const int d = (blockIdx.x & 3) * 128 + threadIdx.x;
    float acc = b_lin[n];
#pragma unroll
    for (int ch = 0; ch < 64; ++ch)
        acc += part[((size_t)ch * NCTX + n) * DIM + d];
    c[(size_t)n * DIM + d] = acc;
}

extern "C" void kernel_launch(void* const* d_in, const int* in_sizes, int n_in,
                              void* d_out, int out_size, void* d_ws, size_t ws_size,
                              hipStream_t stream) {
    const int*   u       = (const int*)  d_in[0];
    const int*   v       = (const int*)  d_in[1];
    const int*   adj_ent = (const int*)  d_in[2];
    const int*   adj_rel = (const int*)  d_in[3];
    const float* usr_emb = (const float*)d_in[4];
    const float* ent_emb = (const float*)d_in[5];
    const float* rel_emb = (const float*)d_in[6];
    const float* W_agg   = (const float*)d_in[7];
    const float* b_agg   = (const float*)d_in[8];
    const float* W_lin   = (const float*)d_in[9];
    const float* b_lin   = (const float*)d_in[10];

    float* out = (float*)d_out;            // [1024]
    float* c   = out + BATCH;              // [16][512]

    // ws layout: hidden_bf (1MB) | Wb (0.5MB) | item fp32 (2MB) | part (2MB)
    ushort* hidden_bf = (ushort*)d_ws;
    ushort* Wb        = hidden_bf + (size_t)BATCH * DIM;
    float*  item      = (float*)(Wb + (size_t)DIM * DIM);
    float*  part      = item + (size_t)BATCH * DIM;

    k_hidden<<<BATCH, 512, 0, stream>>>(u, v, adj_ent, adj_rel,
                                        usr_emb, ent_emb, rel_emb, W_agg,
                                        hidden_bf, Wb);
    k_item_mfma<<<dim3(BATCH / 64, DIM / 64), 256, 0, stream>>>(hidden_bf, Wb, b_agg, item);
    k_out<<<BATCH / 4, 256, 0, stream>>>(u, usr_emb, item, out);
    k_ctx_part<<<64, 512, 0, stream>>>(item, W_lin, part);
    k_ctx_reduce<<<64, 128, 0, stream>>>(part, b_lin, c);
}

// Round 3
// 33.713 us; speedup vs baseline: 1.9099x; 1.5059x over previous
//
#include <hip/hip_runtime.h>
#include <math.h>

#define DIM 512
#define NNBR 8
#define NCTX 16
#define BATCH 1024

typedef __attribute__((ext_vector_type(8))) short bf16x8;
typedef __attribute__((ext_vector_type(4))) float f32x4;

// RNE float -> bf16 bits
static __device__ __forceinline__ ushort f2bf(float f) {
    uint u = __float_as_uint(f);
    return (ushort)((u + 0x7fffu + ((u >> 16) & 1u)) >> 16);
}

// ---------------- KA: hidden_bf + W_agg->bf16 + zero accumulators ----------------
// one block (512 threads = 8 waves) per batch row; thread t <-> dim d.
__global__ __launch_bounds__(512) void k_hidden(
    const int* __restrict__ u, const int* __restrict__ v,
    const int* __restrict__ adj_ent, const int* __restrict__ adj_rel,
    const float* __restrict__ usr_emb, const float* __restrict__ ent_emb,
    const float* __restrict__ rel_emb, const float* __restrict__ W_agg,
    ushort* __restrict__ hidden_bf, ushort* __restrict__ Wb,
    float* __restrict__ out_acc, float* __restrict__ c_acc)
{
    const int b = blockIdx.x;
    const int t = threadIdx.x;           // d index
    if (b < 512) {                        // W_agg -> bf16 (512*512 elems)
        const size_t wi = (size_t)b * 512 + t;
        Wb[wi] = f2bf(W_agg[wi]);
    }
    if (b == 0) { out_acc[t] = 0.0f; out_acc[512 + t] = 0.0f; }
    if (b >= 1 && b <= 16) c_acc[(size_t)(b - 1) * 512 + t] = 0.0f;

    __shared__ int s_ne[NNBR], s_nr[NNBR];
    __shared__ float s_sc[NNBR];
    const int vid = v[b];
    const int uid = u[b];
    if (t < NNBR) {
        s_ne[t] = adj_ent[vid * NNBR + t];
        s_nr[t] = adj_rel[vid * NNBR + t];
        s_sc[t] = 0.0f;
    }
    __syncthreads();

    const float user_d = usr_emb[(size_t)uid * DIM + t];
    const float self_d = ent_emb[(size_t)vid * DIM + t];
    float nbr[NNBR], p[NNBR];
#pragma unroll
    for (int k = 0; k < NNBR; ++k) {
        nbr[k] = ent_emb[(size_t)s_ne[k] * DIM + t];
        p[k] = user_d * rel_emb[(size_t)s_nr[k] * DIM + t];
    }
#pragma unroll
    for (int k = 0; k < NNBR; ++k) {
#pragma unroll
        for (int off = 32; off >= 1; off >>= 1)
            p[k] += __shfl_xor(p[k], off, 64);
    }
    if ((t & 63) == 0) {
#pragma unroll
        for (int k = 0; k < NNBR; ++k) atomicAdd(&s_sc[k], p[k]);
    }
    __syncthreads();

    float m = s_sc[0];
#pragma unroll
    for (int k = 1; k < NNBR; ++k) m = fmaxf(m, s_sc[k]);
    float e[NNBR], ssum = 0.0f;
#pragma unroll
    for (int k = 0; k < NNBR; ++k) { e[k] = expf(s_sc[k] - m); ssum += e[k]; }
    const float inv = 1.0f / ssum;
    float agg = 0.0f;
#pragma unroll
    for (int k = 0; k < NNBR; ++k) agg = fmaf(e[k], nbr[k], agg);

    hidden_bf[(size_t)b * DIM + t] = f2bf(self_d + agg * inv);
}

// ---------------- KB: fused bf16-MFMA GEMM + tanh + out-dot + c-partials ----------------
// 256 thr = 4 waves (2x2 of 32x32), block tile 64x64. item never materialized:
// epilogue computes user.item row-partials (atomicAdd out_acc) and
// W_lin-weighted col-partials (LDS stage -> atomicAdd c_acc).
__global__ __launch_bounds__(256) void k_item_fused(
    const ushort* __restrict__ hidden, const ushort* __restrict__ Wb,
    const float* __restrict__ b_agg, const int* __restrict__ u,
    const float* __restrict__ usr_emb, const float* __restrict__ W_lin,
    float* __restrict__ out_acc, float* __restrict__ c_acc)
{
    __shared__ float c_blk[2][NCTX][64];
    const int tid = threadIdx.x;
    const int lane = tid & 63, w = tid >> 6;
    const int wr = w >> 1, wc = w & 1;
    const int m0 = blockIdx.x * 64 + wr * 32;
    const int n0 = blockIdx.y * 64 + wc * 32;
    const int r = lane & 15;             // A-row / B-col within frag
    const int kb = lane >> 4;            // k-block (8 elems each)

    f32x4 acc[2][2] = {};
    const ushort* Ap = hidden + (size_t)(m0 + r) * DIM + kb * 8;
    const ushort* Bp = Wb     + (size_t)(n0 + r) * DIM + kb * 8;

#pragma unroll
    for (int k0 = 0; k0 < DIM; k0 += 32) {
        bf16x8 a0 = *(const bf16x8*)(Ap + k0);
        bf16x8 a1 = *(const bf16x8*)(Ap + 16 * DIM + k0);
        bf16x8 b0 = *(const bf16x8*)(Bp + k0);
        bf16x8 b1 = *(const bf16x8*)(Bp + 16 * DIM + k0);
        acc[0][0] = __builtin_amdgcn_mfma_f32_16x16x32_bf16(a0, b0, acc[0][0], 0, 0, 0);
        acc[0][1] = __builtin_amdgcn_mfma_f32_16x16x32_bf16(a0, b1, acc[0][1], 0, 0, 0);
        acc[1][0] = __builtin_amdgcn_mfma_f32_16x16x32_bf16(a1, b0, acc[1][0], 0, 0, 0);
        acc[1][1] = __builtin_amdgcn_mfma_f32_16x16x32_bf16(a1, b1, acc[1][1], 0, 0, 0);
    }

    // C/D layout: col = lane&15, row = (lane>>4)*4 + reg
    float cacc[NCTX][2] = {};            // [n][ni] partial over this lane's 8 rows
#pragma unroll
    for (int mi = 0; mi < 2; ++mi)
#pragma unroll
        for (int j = 0; j < 4; ++j) {
            const int row = m0 + mi * 16 + kb * 4 + j;
            const int uid = u[row];
            float vals[2];
            float dp = 0.0f;
#pragma unroll
            for (int ni = 0; ni < 2; ++ni) {
                const int col = n0 + ni * 16 + r;
                const float vv = tanhf(acc[mi][ni][j] + b_agg[col]);
                vals[ni] = vv;
                dp = fmaf(vv, usr_emb[(size_t)uid * DIM + col], dp);
            }
#pragma unroll
            for (int n = 0; n < NCTX; ++n) {
                const float wl = W_lin[n * BATCH + row];   // uniform across 16-lane group
                cacc[n][0] = fmaf(wl, vals[0], cacc[n][0]);
                cacc[n][1] = fmaf(wl, vals[1], cacc[n][1]);
            }
            // reduce dp over the 16 lanes sharing this row (cols)
            dp += __shfl_xor(dp, 1, 64);
            dp += __shfl_xor(dp, 2, 64);
            dp += __shfl_xor(dp, 4, 64);
            dp += __shfl_xor(dp, 8, 64);
            if (r == 0) atomicAdd(&out_acc[row], dp);
        }

    // reduce cacc across the 4 lanes sharing a col (row-groups), stage to LDS
#pragma unroll
    for (int n = 0; n < NCTX; ++n)
#pragma unroll
        for (int ni = 0; ni < 2; ++ni) {
            float vv = cacc[n][ni];
            vv += __shfl_xor(vv, 16, 64);
            vv += __shfl_xor(vv, 32, 64);
            if (kb == 0) c_blk[wr][n][wc * 32 + ni * 16 + r] = vv;
        }
    __syncthreads();

    // 256 threads x 4 elems: sum wr halves, one atomic per (n,col) per block
    const int base = tid * 4;
#pragma unroll
    for (int e = 0; e < 4; ++e) {
        const int idx = base + e;            // n*64 + col
        const int n = idx >> 6, col = idx & 63;
        atomicAdd(&c_acc[(size_t)n * DIM + blockIdx.y * 64 + col],
                  c_blk[0][n][col] + c_blk[1][n][col]);
    }
}

// ---------------- KC: finisher — sigmoid(out_acc) and c = c_acc + b_lin ----------------
__global__ __launch_bounds__(256) void k_finish(
    const float* __restrict__ out_acc, const float* __restrict__ c_acc,
    const float* __restrict__ b_lin, float* __restrict__ out, float* __restrict__ c)
{
    const int i = blockIdx.x * 256 + threadIdx.x;
    if (blockIdx.x < 4) {
        out[i] = 1.0f / (1.0f + expf(-out_acc[i]));
    } else {
        const int idx = i - 1024;            // 0..8191
        const int n = idx >> 9;
        c[idx] = c_acc[idx] + b_lin[n];
    }
}

extern "C" void kernel_launch(void* const* d_in, const int* in_sizes, int n_in,
                              void* d_out, int out_size, void* d_ws, size_t ws_size,
                              hipStream_t stream) {
    const int*   u       = (const int*)  d_in[0];
    const int*   v       = (const int*)  d_in[1];
    const int*   adj_ent = (const int*)  d_in[2];
    const int*   adj_rel = (const int*)  d_in[3];
    const float* usr_emb = (const float*)d_in[4];
    const float* ent_emb = (const float*)d_in[5];
    const float* rel_emb = (const float*)d_in[6];
    const float* W_agg   = (const float*)d_in[7];
    const float* b_agg   = (const float*)d_in[8];
    const float* W_lin   = (const float*)d_in[9];
    const float* b_lin   = (const float*)d_in[10];

    float* out = (float*)d_out;            // [1024]
    float* c   = out + BATCH;              // [16][512]

    // ws layout: hidden_bf (1MB) | Wb (0.5MB) | out_acc (4KB) | c_acc (32KB)
    ushort* hidden_bf = (ushort*)d_ws;
    ushort* Wb        = hidden_bf + (size_t)BATCH * DIM;
    float*  out_acc   = (float*)(Wb + (size_t)DIM * DIM);
    float*  c_acc     = out_acc + BATCH;

    k_hidden<<<BATCH, 512, 0, stream>>>(u, v, adj_ent, adj_rel,
                                        usr_emb, ent_emb, rel_emb, W_agg,
                                        hidden_bf, Wb, out_acc, c_acc);
    k_item_fused<<<dim3(BATCH / 64, DIM / 64), 256, 0, stream>>>(
        hidden_bf, Wb, b_agg, u, usr_emb, W_lin, out_acc, c_acc);
    k_finish<<<36, 256, 0, stream>>>(out_acc, c_acc, b_lin, out, c);
}